// Round 4
// baseline (299.587 us; speedup 1.0000x reference)
//
#include <hip/hip_runtime.h>
#include <hip/hip_bf16.h>
#include <math.h>

#define TN 201
#define NSTEP 200
#define BATCH 4096
#define DIM 20
#define HID 128
#define NCH 12

typedef __attribute__((ext_vector_type(8))) short short8;
typedef __attribute__((ext_vector_type(4))) float f32x4;
union S8U { short8 s; unsigned u[4]; };

__device__ __forceinline__ unsigned pk2(float lo, float hi) {
  __hip_bfloat162 h = __float22bfloat162_rn(make_float2(lo, hi));
  union { __hip_bfloat162 h; unsigned u; } v;
  v.h = h;
  return v.u;
}
__device__ __forceinline__ float tanh_fast(float x) {
  float e = __builtin_amdgcn_exp2f(x * 2.8853900817779268f);
  return 1.f - 2.f * __builtin_amdgcn_rcpf(e + 1.f);
}

// ws layout (floats):
//   [0..399]     Pp  = sigma^T P
//   [400..799]   Mp  = -sigma^T A sigma^{-T}
//   [800..1199]  Qp  = sigma^T Q
//   [1200..1399] dt[200]
//   [1400..1599] 1/sqrt(dt)[200]
//   [1600..1631] b2p = sigma^T b2 (padded to 32, zeros beyond 20)
//   [2048..4607] W2p = W2 sigma  [128][20]
//   [8192 ...]   zc: A1[12][81920], A2[12][81920], S[12][81920]

// ================= k0: setup =================
__global__ __launch_bounds__(256) void k0_setup(
    const float* __restrict__ ts, const float* __restrict__ sigma,
    const float* __restrict__ A, const float* __restrict__ P,
    const float* __restrict__ Q, const float* __restrict__ W2,
    const float* __restrict__ b2, float* __restrict__ wsc) {
  __shared__ float aug[20][40];
  __shared__ float sS[400], sA[400], sT1[400];
  __shared__ float fac[20];
  __shared__ float piv;
  int tid = threadIdx.x;
  for (int e = tid; e < 400; e += 256) { sS[e] = sigma[e]; sA[e] = A[e]; }
  for (int e = tid; e < 800; e += 256) {
    int i = e / 40, j = e % 40;
    aug[i][j] = (j < 20) ? sigma[i * 20 + j] : ((j - 20) == i ? 1.f : 0.f);
  }
  __syncthreads();
  for (int p = 0; p < 20; ++p) {
    if (tid == 0) piv = 1.f / aug[p][p];
    __syncthreads();
    if (tid < 40) aug[p][tid] *= piv;
    __syncthreads();
    if (tid < 20) fac[tid] = aug[tid][p];
    __syncthreads();
    for (int e = tid; e < 800; e += 256) {
      int i = e / 40, j = e % 40;
      if (i != p) aug[i][j] -= fac[i] * aug[p][j];
    }
    __syncthreads();
  }
  // T1[k][j] = (A sigma^{-T})[k][j]
  for (int e = tid; e < 400; e += 256) {
    int k = e / 20, j = e % 20;
    float s = 0.f;
    for (int l2 = 0; l2 < 20; ++l2) s += sA[k * 20 + l2] * aug[j][20 + l2];
    sT1[e] = s;
  }
  __syncthreads();
  for (int e = tid; e < 400; e += 256) {
    int i = e / 20, j = e % 20;
    float m = 0.f, pp = 0.f, qq = 0.f;
    for (int k = 0; k < 20; ++k) {
      float sk = sS[k * 20 + i];
      m += sk * sT1[k * 20 + j];
      pp += sk * P[k * 20 + j];
      qq += sk * Q[k * 20 + j];
    }
    wsc[e] = pp;
    wsc[400 + e] = -m;
    wsc[800 + e] = qq;
  }
  for (int e = tid; e < 2560; e += 256) {
    int h = e / 20, i = e % 20;
    float s = 0.f;
    for (int j = 0; j < 20; ++j) s += W2[h * 20 + j] * sS[j * 20 + i];
    wsc[2048 + e] = s;
  }
  if (tid < 32) {
    float s = 0.f;
    if (tid < 20)
      for (int j = 0; j < 20; ++j) s += b2[j] * sS[j * 20 + tid];
    wsc[1600 + tid] = s;
  }
  if (tid < NSTEP) {
    float d = ts[tid + 1] - ts[tid];
    wsc[1200 + tid] = d;
    wsc[1400 + tid] = rsqrtf(d);
  }
}

#define MFMA16(a, b, c) __builtin_amdgcn_mfma_f32_16x16x32_bf16((a), (b), (c), 0, 0, 0)

// ================= kernel A: all-register fused MLP + integrand + chunk scan =====
// Orientation: D[m][n] with m = hidden/dim, n = batch. Lane (quad q, m16):
//   layer1 C: hiddens 32p+4q+reg for batch m16  -> directly a layer2 B-frag
//   (k-permutation hid(k)=32p+(j>=4?16:0)+4q+(j&3) applied identically to W2p A-frag).
// No LDS, no __syncthreads, no cross-lane ops in the whole kernel.
__global__ __launch_bounds__(256, 3) void kA(
    const float* __restrict__ states, const float* __restrict__ noises,
    const float* __restrict__ controls, const float* __restrict__ ts,
    const float* __restrict__ W1, const float* __restrict__ b1,
    const float* __restrict__ wsc, float* __restrict__ zc) {
  const int tid = threadIdx.x;
  const int l = tid & 63;
  const int w = tid >> 6;
  const int quad = l >> 4;
  const int m16 = l & 15;

  const int c = blockIdx.x >> 6;     // 0..11 chunks (c=0 = highest t)
  const int slab = blockIdx.x & 63;  // 0..63
  const int bb = slab * 64 + w * 16 + m16;  // this lane's batch
  const int thi = (c < 9) ? (200 - 17 * c) : (47 - 16 * (c - 9));
  const int tlo = thi - ((c < 9) ? 16 : 15);

  const float* W2p = wsc + 2048;
  const float* Pp = wsc;
  const float* Mp = wsc + 400;

  // ---- prologue: A-side fragments in VGPRs ----
  // W1^T frags: A[m=hidden 16t+m16][k], input order: k<20 -> x_k (W1 row k+1),
  // k==20 -> t (W1 row 0), k==21 -> 1.0 (b1), else 0.
  short8 W1f[8];
#pragma unroll
  for (int tt = 0; tt < 8; ++tt) {
    S8U f;
    int h = 16 * tt + m16;
#pragma unroll
    for (int jj = 0; jj < 4; ++jj) {
      float v[2];
#pragma unroll
      for (int hh = 0; hh < 2; ++hh) {
        int e = 8 * quad + 2 * jj + hh;
        float x;
        if (e < 20) x = W1[(e + 1) * HID + h];
        else if (e == 20) x = W1[h];
        else if (e == 21) x = b1[h];
        else x = 0.f;
        v[hh] = x;
      }
      f.u[jj] = pk2(v[0], v[1]);
    }
    W1f[tt] = f.s;
  }
  // W2p^T frags with the K-permutation (see header comment)
  short8 W2f[4][2];
#pragma unroll
  for (int p = 0; p < 4; ++p)
#pragma unroll
    for (int mt = 0; mt < 2; ++mt) {
      int dim = (mt == 0) ? m16 : (m16 < 4 ? 16 + m16 : -1);
      S8U f;
#pragma unroll
      for (int jj = 0; jj < 4; ++jj) {
        float v[2];
#pragma unroll
        for (int hh = 0; hh < 2; ++hh) {
          int j = 2 * jj + hh;
          int hid = 32 * p + ((j >= 4) ? 16 : 0) + 4 * quad + (j & 3);
          v[hh] = (dim >= 0) ? W2p[hid * 20 + dim] : 0.f;
        }
        f.u[jj] = pk2(v[0], v[1]);
      }
      W2f[p][mt] = f.s;
    }
  // Integrand A-frags: A[dim][k], k<20 -> Pp[dim][k], 20..39 -> Mp[dim][k-20]
  short8 Bsf[2][2];
#pragma unroll
  for (int kc = 0; kc < 2; ++kc)
#pragma unroll
    for (int mt = 0; mt < 2; ++mt) {
      int dim = (mt == 0) ? m16 : (m16 < 4 ? 16 + m16 : -1);
      S8U f;
#pragma unroll
      for (int jj = 0; jj < 4; ++jj) {
        float v[2];
#pragma unroll
        for (int hh = 0; hh < 2; ++hh) {
          int k = 32 * kc + 8 * quad + 2 * jj + hh;
          float x = 0.f;
          if (dim >= 0) {
            if (k < 20) x = Pp[dim * 20 + k];
            else if (k < 40) x = Mp[dim * 20 + (k - 20)];
          }
          v[hh] = x;
        }
        f.u[jj] = pk2(v[0], v[1]);
      }
      Bsf[kc][mt] = f.s;
    }

  // per-quad load windows (all 16B-aligned, all in-row)
  const int xo1 = (8 * quad < 16) ? 8 * quad : 16;
  const int xo2 = (8 * quad + 4 < 16) ? 8 * quad + 4 : 16;
  const int no = (quad == 2) ? 0 : ((quad == 3) ? 4 : 12);
  const size_t rstride = (size_t)BATCH * 20;

  const float* xrp = states + (size_t)thi * rstride + (size_t)bb * 20;
  float4 xa = *(const float4*)(xrp + xo1);
  float4 xb = *(const float4*)(xrp + xo2);
  float4 na = make_float4(0.f, 0.f, 0.f, 0.f), nb = na, ca = na, cb = na;
  if (thi < NSTEP) {
    const float* nrp = noises + (size_t)thi * rstride + (size_t)bb * 20;
    const float* crp = controls + (size_t)thi * rstride + (size_t)bb * 20;
    na = *(const float4*)(nrp + no);
    nb = *(const float4*)(nrp + no + 4);
    ca = *(const float4*)(crp + no);
    cb = *(const float4*)(crp + no + 4);
  }

  f32x4 A1a = {0.f, 0.f, 0.f, 0.f}, A1b = A1a;
  f32x4 A2a = A1a, A2b = A1a, La = A1a, Lb = A1a;
  const f32x4 zero = {0.f, 0.f, 0.f, 0.f};

#pragma unroll 1
  for (int t = thi; t >= tlo; --t) {
    const bool has_s = (t < NSTEP);
    const float tval = ts[t];
    const float dtv = has_s ? wsc[1200 + t] : 0.f;
    const float rsd = has_s ? wsc[1400 + t] : 0.f;

    unsigned pxa01 = pk2(xa.x, xa.y), pxa23 = pk2(xa.z, xa.w);
    unsigned pxb01 = pk2(xb.x, xb.y), pxb23 = pk2(xb.z, xb.w);
    unsigned pT1 = pk2(tval, 1.f);
    S8U mA;  // MLP B-frag: [x0..x19, t, 1, 0...]
    mA.u[0] = (quad == 3) ? 0u : pxa01;
    mA.u[1] = (quad == 3) ? 0u : pxa23;
    mA.u[2] = (quad < 2) ? pxb01 : ((quad == 2) ? pT1 : 0u);
    mA.u[3] = (quad < 2) ? pxb23 : 0u;

    S8U k0f, k1f;  // integrand B-frags: [x0..19 | y0..19 | 0...]
    if (has_s) {
      float y0 = fmaf(na.x, rsd, ca.x), y1 = fmaf(na.y, rsd, ca.y);
      float y2 = fmaf(na.z, rsd, ca.z), y3 = fmaf(na.w, rsd, ca.w);
      float y4 = fmaf(nb.x, rsd, cb.x), y5 = fmaf(nb.y, rsd, cb.y);
      float y6 = fmaf(nb.z, rsd, cb.z), y7 = fmaf(nb.w, rsd, cb.w);
      unsigned py01 = pk2(y0, y1), py23 = pk2(y2, y3);
      unsigned py45 = pk2(y4, y5), py67 = pk2(y6, y7);
      k0f.u[0] = (quad == 3) ? py01 : pxa01;
      k0f.u[1] = (quad == 3) ? py23 : pxa23;
      k0f.u[2] = (quad < 2) ? pxb01 : ((quad == 2) ? py01 : py45);
      k0f.u[3] = (quad < 2) ? pxb23 : ((quad == 2) ? py23 : py67);
      k1f.u[0] = (quad == 0) ? py01 : 0u;
      k1f.u[1] = (quad == 0) ? py23 : 0u;
      k1f.u[2] = (quad == 0) ? py45 : 0u;
      k1f.u[3] = (quad == 0) ? py67 : 0u;
    } else {
      k0f.u[0] = k0f.u[1] = k0f.u[2] = k0f.u[3] = 0u;
      k1f.u[0] = k1f.u[1] = k1f.u[2] = k1f.u[3] = 0u;
    }

    // issue next-t loads now; compute below hides them
    if (t > tlo) {
      const float* xr = states + (size_t)(t - 1) * rstride + (size_t)bb * 20;
      const float* nr = noises + (size_t)(t - 1) * rstride + (size_t)bb * 20;
      const float* cr = controls + (size_t)(t - 1) * rstride + (size_t)bb * 20;
      xa = *(const float4*)(xr + xo1);
      xb = *(const float4*)(xr + xo2);
      na = *(const float4*)(nr + no);
      nb = *(const float4*)(nr + no + 4);
      ca = *(const float4*)(cr + no);
      cb = *(const float4*)(cr + no + 4);
    }

    // ---- MLP, fully in registers ----
    f32x4 u0 = zero, u1 = zero;  // b2p folded into kB's term
#pragma unroll
    for (int p = 0; p < 4; ++p) {
      f32x4 cA = MFMA16(W1f[2 * p], mA.s, zero);
      f32x4 cB = MFMA16(W1f[2 * p + 1], mA.s, zero);
      S8U hf;
      hf.u[0] = pk2(tanh_fast(cA[0]), tanh_fast(cA[1]));
      hf.u[1] = pk2(tanh_fast(cA[2]), tanh_fast(cA[3]));
      hf.u[2] = pk2(tanh_fast(cB[0]), tanh_fast(cB[1]));
      hf.u[3] = pk2(tanh_fast(cB[2]), tanh_fast(cB[3]));
      u0 = MFMA16(W2f[p][0], hf.s, u0);
      u1 = MFMA16(W2f[p][1], hf.s, u1);
    }

    // ---- integrand + scan update ----
    if (has_s) {
      f32x4 a0 = MFMA16(Bsf[0][0], k0f.s, zero);
      a0 = MFMA16(Bsf[1][0], k1f.s, a0);
      f32x4 a1 = MFMA16(Bsf[0][1], k0f.s, zero);
      a1 = MFMA16(Bsf[1][1], k1f.s, a1);
      La += a0 * dtv;
      Lb += a1 * dtv;
    }
    f32x4 p0 = u0 - La, p1 = u1 - Lb;
    A2a += p0;
    A2b += p1;
    A1a += p0 * p0;
    A1b += p1 * p1;
  }

  // ---- epilogue ----
  float* zA1 = zc;
  float* zA2 = zc + (size_t)NCH * BATCH * DIM;
  float* zS = zc + (size_t)2 * NCH * BATCH * DIM;
  size_t base = ((size_t)c * BATCH + bb) * 20;
#pragma unroll
  for (int r = 0; r < 4; ++r) {
    int d = 4 * quad + r;
    zA1[base + d] = A1a[r];
    zA2[base + d] = A2a[r];
    zS[base + d] = La[r];
  }
  if (quad == 0) {
#pragma unroll
    for (int r = 0; r < 4; ++r) {
      zA1[base + 16 + r] = A1b[r];
      zA2[base + 16 + r] = A2b[r];
      zS[base + 16 + r] = Lb[r];
    }
  }
}

// ================= kernel B: combine chunks =================
__global__ __launch_bounds__(256) void kB(
    const float* __restrict__ states, const float* __restrict__ lw,
    const float* __restrict__ wsc, const float* __restrict__ zc,
    float* __restrict__ out) {
  __shared__ float sQp[400];
  int tid = threadIdx.x;
  for (int e = tid; e < 400; e += 256) sQp[e] = wsc[800 + e];
  __syncthreads();
  const int u = blockIdx.x * 256 + tid;  // < 81920
  const int b = u / 20;
  const int i = u - b * 20;
  const float* xp = states + ((size_t)NSTEP * BATCH + b) * 20;
  float term = -wsc[1600 + i];  // -b2p[i] (bias folded out of kA's u)
#pragma unroll
  for (int j = 0; j < 20; ++j) term = fmaf(sQp[i * 20 + j], xp[j], term);

  const size_t CH = (size_t)BATCH * DIM;  // 81920
  float T = 0.f, obj = 0.f;
#pragma unroll
  for (int c = 0; c < NCH; ++c) {
    float A1 = zc[(size_t)c * CH + u];
    float A2 = zc[(size_t)(NCH + c) * CH + u];
    float S = zc[(size_t)(2 * NCH + c) * CH + u];
    float K = term + T;
    float nc = (c < 9) ? 17.f : 16.f;
    obj += A1 - 2.f * K * A2 + nc * K * K;
    T += S;
  }
  obj *= __expf(lw[b]) * (1.f / ((float)TN * (float)BATCH));
#pragma unroll
  for (int off = 32; off > 0; off >>= 1) obj += __shfl_down(obj, off, 64);
  if ((tid & 63) == 0) atomicAdd(out, obj);
}

extern "C" void kernel_launch(void* const* d_in, const int* in_sizes, int n_in,
                              void* d_out, int out_size, void* d_ws, size_t ws_size,
                              hipStream_t stream) {
  const float* states = (const float*)d_in[0];
  const float* noises = (const float*)d_in[1];
  const float* controls = (const float*)d_in[2];
  const float* lw = (const float*)d_in[3];
  const float* ts = (const float*)d_in[4];
  const float* sigma = (const float*)d_in[5];
  const float* P = (const float*)d_in[6];
  const float* A = (const float*)d_in[7];
  const float* Q = (const float*)d_in[8];
  const float* W1 = (const float*)d_in[9];
  const float* b1 = (const float*)d_in[10];
  const float* W2 = (const float*)d_in[11];
  const float* b2 = (const float*)d_in[12];
  float* out = (float*)d_out;

  float* wsc = (float*)d_ws;
  float* zc = wsc + 8192;

  hipMemsetAsync(out, 0, sizeof(float), stream);
  hipLaunchKernelGGL(k0_setup, dim3(1), dim3(256), 0, stream,
                     ts, sigma, A, P, Q, W2, b2, wsc);
  hipLaunchKernelGGL(kA, dim3(NCH * 64), dim3(256), 0, stream,
                     states, noises, controls, ts, W1, b1, wsc, zc);
  hipLaunchKernelGGL(kB, dim3((BATCH * DIM) / 256), dim3(256), 0, stream,
                     states, lw, wsc, zc, out);
}